// Round 7
// baseline (21.941 us; speedup 1.0000x reference)
//
#include <hip/hip_runtime.h>

#define ALPHA  0.7f
#define MARGIN 0.5f
#define TI  64     // i-tile height (wave-uniform scalar loads)
#define TJ  512    // j-tile width = 256 threads * JR
#define JR  2      // j's per thread (float2, packed-f32 math)

typedef float    v2f __attribute__((ext_vector_type(2)));
typedef unsigned v2u __attribute__((ext_vector_type(2)));

// Triangular tiling, 256-thread blocks, 8 blocks/CU resident (one round).
// Column jt (j in [jt*512,(jt+1)*512)): i-tiles it = 0..8*jt+7 (64 rows).
//   it <  8*jt -> full tile (all i < all j, no predicate)
//   it >= 8*jt -> partial   (per-pair i<j predicate)
// Column start K(jt) = 4*jt*(jt+1). NB = 4*NJ*(NJ+1). B=8192 -> 1088 blocks.
__global__ __launch_bounds__(256, 8)
void pair_kernel(const float* __restrict__ p, const float* __restrict__ t,
                 int B, float4* __restrict__ bout) {
    const int bid = blockIdx.x;
    int jt = (int)((sqrtf((float)bid + 1.0f) - 1.0f) * 0.5f);
    while (4 * (jt + 1) * (jt + 2) <= bid) ++jt;
    while (4 * jt * (jt + 1) > bid) --jt;
    const int it = bid - 4 * jt * (jt + 1);

    const int tid   = threadIdx.x;         // 0..255
    const int ibase = it * TI;
    const int j0    = jt * TJ + tid * JR;

    // j-data in registers; invalid j padded so hinge==0 and dt!=0:
    //   tj=+inf -> dt=-inf (never a tie), sg=1 -> sdp=-dp=+huge -> v=0
    v2f tj, pj;
    bool jv0, jv1;
    if (j0 + JR <= B) {
        const float2 tv = *reinterpret_cast<const float2*>(t + j0);
        const float2 pv = *reinterpret_cast<const float2*>(p + j0);
        tj[0] = tv.x; tj[1] = tv.y; pj[0] = pv.x; pj[1] = pv.y;
        jv0 = jv1 = true;
    } else {
        jv0 = (j0 + 0) < B;
        jv1 = (j0 + 1) < B;
        tj[0] = jv0 ? t[j0]     : __int_as_float(0x7f800000);
        tj[1] = jv1 ? t[j0 + 1] : __int_as_float(0x7f800000);
        pj[0] = jv0 ? p[j0]     : 1e30f;
        pj[1] = jv1 ? p[j0 + 1] : 1e30f;
    }

    v2f  sum2 = {0.0f, 0.0f};
    float msev = 0.0f;
    int  cnt = 0, tiec = 0;

    if (it == 0) {                       // one tile per column folds the MSE
        const float d0 = pj[0] - tj[0], d1 = pj[1] - tj[1];
        msev += jv0 ? d0 * d0 : 0.0f;
        msev += jv1 ? d1 * d1 : 0.0f;
    }

    const int ilim = min(TI, B - ibase);

    if (it < 8 * jt) {
        // ---------- full tile: packed 2-pair body, no predicate ----------
        #pragma unroll 8
        for (int ii = 0; ii < TI; ++ii) {
            const float ts = t[ibase + ii];     // wave-uniform -> s_load
            const float ps = p[ibase + ii];
            const v2f dt = ts - tj;             // v_pk_add (neg)
            const v2f dp = ps - pj;
            v2u du = __builtin_bit_cast(v2u, dp);
            const v2u su = __builtin_bit_cast(v2u, dt) & 0x80000000u;
            du ^= su;                           // sdp = sign(dt)*dp
            const v2f sdp = __builtin_bit_cast(v2f, du);
            v2f h = MARGIN - sdp;               // v_pk_add
            v2f v;
            v[0] = fmaxf(h[0], 0.0f);           // v_pk_max_f32 (SLP)
            v[1] = fmaxf(h[1], 0.0f);
            sum2 += v;                          // v_pk_add
            const bool e0 = (dt[0] == 0.0f);
            const bool e1 = (dt[1] == 0.0f);
            if (__any(e0 || e1)) {              // rare exact-tie fixup
                sum2[0] -= e0 ? v[0] : 0.0f;
                sum2[1] -= e1 ? v[1] : 0.0f;
                tiec += (e0 ? 1 : 0) + (e1 ? 1 : 0);
            }
        }
        cnt += (jv0 ? TI : 0) + (jv1 ? TI : 0);
    } else if (ilim > 0) {
        // ---------- partial tile: global i<j predicate ----------
        const int jl0 = j0 - ibase;             // pair valid iff ii < jl0
        const int jl1 = jl0 + 1;
        #pragma unroll 4
        for (int ii = 0; ii < ilim; ++ii) {
            const float ts = t[ibase + ii];
            const float ps = p[ibase + ii];
            const v2f dt = ts - tj;
            const v2f dp = ps - pj;
            v2u du = __builtin_bit_cast(v2u, dp);
            const v2u su = __builtin_bit_cast(v2u, dt) & 0x80000000u;
            du ^= su;
            const v2f sdp = __builtin_bit_cast(v2f, du);
            v2f h = MARGIN - sdp;
            v2f v;
            v[0] = fmaxf(h[0], 0.0f);
            v[1] = fmaxf(h[1], 0.0f);
            const bool in0 = ii < jl0;
            const bool in1 = ii < jl1;
            sum2[0] += in0 ? v[0] : 0.0f;
            sum2[1] += in1 ? v[1] : 0.0f;
            const bool e0 = (dt[0] == 0.0f) && in0;
            const bool e1 = (dt[1] == 0.0f) && in1;
            if (__any(e0 || e1)) {              // rare exact-tie fixup
                sum2[0] -= e0 ? v[0] : 0.0f;
                sum2[1] -= e1 ? v[1] : 0.0f;
                tiec += (e0 ? 1 : 0) + (e1 ? 1 : 0);
            }
        }
        int c0 = min(max(jl0, 0), ilim);
        int c1 = min(max(jl1, 0), ilim);
        cnt += (jv0 ? c0 : 0) + (jv1 ? c1 : 0);
    }

    // epilogue: wave butterfly, then cross-wave via LDS
    float sum = sum2[0] + sum2[1];
    int cn = cnt - tiec;
    for (int off = 32; off > 0; off >>= 1) {
        sum  += __shfl_down(sum, off);
        msev += __shfl_down(msev, off);
        cn   += __shfl_down(cn, off);
    }
    __shared__ float rs[4], rm[4];
    __shared__ int   rc[4];
    const int wid = tid >> 6, lane = tid & 63;
    if (lane == 0) { rs[wid] = sum; rm[wid] = msev; rc[wid] = cn; }
    __syncthreads();
    if (tid == 0) {
        float4 o;
        o.x = rs[0] + rs[1] + rs[2] + rs[3];
        o.y = rm[0] + rm[1] + rm[2] + rm[3];
        o.z = (float)(rc[0] + rc[1] + rc[2] + rc[3]);  // <= 32768, f32-exact
        o.w = 0.0f;
        bout[bid] = o;
    }
}

// Fixed-order deterministic tree reduction over NB float4 partials.
__global__ __launch_bounds__(256) void finalize_kernel(const float4* __restrict__ bout,
                                                       int NB, int B,
                                                       float* __restrict__ out) {
    const int tid = threadIdx.x;
    double S = 0.0, M = 0.0, C = 0.0;
    for (int k = tid; k < NB; k += 256) {
        const float4 o = bout[k];
        S += (double)o.x;
        M += (double)o.y;
        C += (double)o.z;
    }
    for (int off = 32; off > 0; off >>= 1) {
        S += __shfl_down(S, off);
        M += __shfl_down(M, off);
        C += __shfl_down(C, off);
    }
    __shared__ double rs[4], rm[4], rc[4];
    const int wid = tid >> 6, lane = tid & 63;
    if (lane == 0) { rs[wid] = S; rm[wid] = M; rc[wid] = C; }
    __syncthreads();
    if (tid == 0) {
        S = rs[0] + rs[1] + rs[2] + rs[3];
        M = rm[0] + rm[1] + rm[2] + rm[3];
        C = rc[0] + rc[1] + rc[2] + rc[3];
        const double mse  = M / (double)B;
        const double rank = (C > 0.0) ? (S / fmax(C, 1.0)) : 0.0;
        out[0] = (float)((double)ALPHA * mse + (double)(1.0f - ALPHA) * rank);
    }
}

extern "C" void kernel_launch(void* const* d_in, const int* in_sizes, int n_in,
                              void* d_out, int out_size, void* d_ws, size_t ws_size,
                              hipStream_t stream) {
    const float* p = (const float*)d_in[0];
    const float* t = (const float*)d_in[1];
    const int B = in_sizes[0];

    const int NJ = (B + TJ - 1) / TJ;
    const int NB = 4 * NJ * (NJ + 1);

    float4* bout = (float4*)d_ws;

    pair_kernel<<<NB, 256, 0, stream>>>(p, t, B, bout);
    finalize_kernel<<<1, 256, 0, stream>>>(bout, NB, B, (float*)d_out);
}

// Round 8
// 19.825 us; speedup vs baseline: 1.1068x; 1.1068x over previous
//
#include <hip/hip_runtime.h>

#define ALPHA 0.7f
#define MARGIN 0.5f
#define TI 128   // i-tile height (staged in LDS)
#define TJ 256   // j-tile width (= threads per block, 1 j per thread)

// Tile decomposition: j-tiles of 256 (one per 256-thread block column),
// i-tiles of 128. For j-tile jt, i-tiles it = 0 .. 2*jt+1 are launched:
//   it <  2*jt      -> full tile (every i < every j, no predicate)
//   it in {2jt,2jt+1} -> partial tile (per-pair i<j predicate)
// Linear block id -> (jt, it): column jt starts at K(jt) = jt*(jt+1).
// Total blocks NB = NJ*(NJ+1), NJ = ceil(B/TJ).  (B=8192 -> 1056 blocks)
__global__ __launch_bounds__(256) void pair_kernel(const float* __restrict__ p,
                                                   const float* __restrict__ t,
                                                   int B,
                                                   float* __restrict__ bsum,
                                                   float* __restrict__ bmse,
                                                   int*   __restrict__ bcnt) {
    const int bid = blockIdx.x;
    // jt = largest jt with jt*(jt+1) <= bid
    int jt = (int)((sqrtf(4.0f * (float)bid + 1.0f) - 1.0f) * 0.5f);
    while ((jt + 1) * (jt + 2) <= bid) ++jt;
    while (jt * (jt + 1) > bid) --jt;
    const int it = bid - jt * (jt + 1);

    const int tid = threadIdx.x;
    const int ig0 = it * TI;
    const int jg  = jt * TJ + tid;

    __shared__ float s_t[TI];
    __shared__ float s_p[TI];
    if (tid < TI) {
        const int ig = ig0 + tid;
        const bool iv = ig < B;
        s_t[tid] = iv ? t[ig] : 0.0f;
        s_p[tid] = iv ? p[ig] : 0.0f;
    }
    __syncthreads();

    const bool jvalid = jg < B;
    const float tjv = jvalid ? t[jg] : 0.0f;
    const float pjv = jvalid ? p[jg] : 0.0f;

    float sum  = 0.0f;
    int   cnt  = 0;
    float msev = 0.0f;

    const bool fulltile = (ig0 + TI) <= jt * TJ;

    if (jvalid) {
        if (it == 2 * jt) {          // exactly one block per j column: fold MSE
            const float d = pjv - tjv;
            msev = d * d;
        }
        if (fulltile) {
            #pragma unroll 8
            for (int ii = 0; ii < TI; ++ii) {
                const float dt = s_t[ii] - tjv;
                const float dp = s_p[ii] - pjv;
                const float sdp = (dt > 0.0f) ? dp : -dp;
                const float v = fmaxf(MARGIN - sdp, 0.0f);
                const bool valid = (dt != 0.0f);
                sum += valid ? v : 0.0f;
                cnt += valid ? 1 : 0;
            }
        } else {
            const int ilim = min(TI, B - ig0);
            const int jloc = jg - ig0;           // pair valid only if ii < jloc
            #pragma unroll 4
            for (int ii = 0; ii < ilim; ++ii) {
                const float dt = s_t[ii] - tjv;
                const float dp = s_p[ii] - pjv;
                const float sdp = (dt > 0.0f) ? dp : -dp;
                const float v = fmaxf(MARGIN - sdp, 0.0f);
                const bool valid = (dt != 0.0f) && (ii < jloc);
                sum += valid ? v : 0.0f;
                cnt += valid ? 1 : 0;
            }
        }
    }

    // 64-lane butterfly reduction
    for (int off = 32; off > 0; off >>= 1) {
        sum  += __shfl_down(sum, off);
        cnt  += __shfl_down(cnt, off);
        msev += __shfl_down(msev, off);
    }
    __shared__ float r_sum[4], r_mse[4];
    __shared__ int   r_cnt[4];
    const int wid  = tid >> 6;
    const int lane = tid & 63;
    if (lane == 0) { r_sum[wid] = sum; r_mse[wid] = msev; r_cnt[wid] = cnt; }
    __syncthreads();
    if (tid == 0) {
        bsum[bid] = r_sum[0] + r_sum[1] + r_sum[2] + r_sum[3];
        bmse[bid] = r_mse[0] + r_mse[1] + r_mse[2] + r_mse[3];
        bcnt[bid] = r_cnt[0] + r_cnt[1] + r_cnt[2] + r_cnt[3];
    }
}

// Fixed-order tree reduction over NB block partials -> deterministic.
__global__ __launch_bounds__(256) void finalize_kernel(const float* __restrict__ bsum,
                                                       const float* __restrict__ bmse,
                                                       const int*   __restrict__ bcnt,
                                                       int NB, int B,
                                                       float* __restrict__ out) {
    const int tid = threadIdx.x;
    double S = 0.0, M = 0.0;
    long long C = 0;
    for (int k = tid; k < NB; k += 256) {
        S += (double)bsum[k];
        M += (double)bmse[k];
        C += (long long)bcnt[k];
    }
    for (int off = 32; off > 0; off >>= 1) {
        S += __shfl_down(S, off);
        M += __shfl_down(M, off);
        C += __shfl_down(C, off);
    }
    __shared__ double rs[4], rm[4];
    __shared__ long long rc[4];
    const int wid = tid >> 6, lane = tid & 63;
    if (lane == 0) { rs[wid] = S; rm[wid] = M; rc[wid] = C; }
    __syncthreads();
    if (tid == 0) {
        S = rs[0] + rs[1] + rs[2] + rs[3];
        M = rm[0] + rm[1] + rm[2] + rm[3];
        C = rc[0] + rc[1] + rc[2] + rc[3];
        const double mse  = M / (double)B;
        const double rank = (C > 0) ? (S / (double)(C > 1 ? C : 1)) : 0.0;
        out[0] = (float)((double)ALPHA * mse + (double)(1.0f - ALPHA) * rank);
    }
}

extern "C" void kernel_launch(void* const* d_in, const int* in_sizes, int n_in,
                              void* d_out, int out_size, void* d_ws, size_t ws_size,
                              hipStream_t stream) {
    const float* p = (const float*)d_in[0];
    const float* t = (const float*)d_in[1];
    const int B = in_sizes[0];

    const int NJ = (B + TJ - 1) / TJ;
    const int NB = NJ * (NJ + 1);

    float* bsum = (float*)d_ws;
    float* bmse = bsum + NB;
    int*   bcnt = (int*)(bmse + NB);

    pair_kernel<<<NB, TJ, 0, stream>>>(p, t, B, bsum, bmse, bcnt);
    finalize_kernel<<<1, 256, 0, stream>>>(bsum, bmse, bcnt, NB, B, (float*)d_out);
}